// Round 1
// baseline (2070.615 us; speedup 1.0000x reference)
//
#include <hip/hip_runtime.h>
#include <hip/hip_bf16.h>

typedef __attribute__((ext_vector_type(8))) __bf16 bf16x8;
typedef __attribute__((ext_vector_type(4))) float f32x4;

constexpr int Nn = 100000;
constexpr int Ee = 1600000;
constexpr int Hd = 128;          // F == H == 128
constexpr int Ll = 4;
constexpr int Gg = 512;
constexpr int Oo = 10;
constexpr int Din = Hd + Ll * Hd; // 640
constexpr int SPLIT = 8;

__device__ __forceinline__ int swzb(int row, int bc) {
  // byte offset into a 128x128 bf16 tile (256 B/row), XOR-swizzled (T2, st-style)
  return (row << 8) + (bc ^ ((row & 7) << 4));
}

__device__ __forceinline__ unsigned short f2bf(float f) {
  __hip_bfloat16 b = __float2bfloat16(f);
  unsigned short u;
  __builtin_memcpy(&u, &b, 2);
  return u;
}

__device__ __forceinline__ int lower_bound_dev(const int* a, int n, int key) {
  int lo = 0, hi = n;
  while (lo < hi) { int mid = (lo + hi) >> 1; if (a[mid] < key) lo = mid + 1; else hi = mid; }
  return lo;
}

// ---- weight prep: W1s/W2s f32 [l][k][n] -> wt bf16 [l][w][n][k] (transposed) ----
__global__ __launch_bounds__(256) void wprep_kernel(const float* __restrict__ W1s,
                                                    const float* __restrict__ W2s,
                                                    __hip_bfloat16* __restrict__ wt) {
  int idx = blockIdx.x * 256 + threadIdx.x;
  if (idx >= Ll * 2 * Hd * Hd) return;
  int l = idx >> 15;
  int w = (idx >> 14) & 1;
  int nn = (idx >> 7) & 127;
  int k = idx & 127;
  const float* W = w ? W2s : W1s;
  wt[idx] = __float2bfloat16(W[l * Hd * Hd + k * Hd + nn]);
}

// ---- CSR build ----
__global__ __launch_bounds__(256) void count_kernel(const int* __restrict__ dst, int* __restrict__ cnt) {
  for (int i = blockIdx.x * blockDim.x + threadIdx.x; i < Ee; i += gridDim.x * blockDim.x)
    atomicAdd(&cnt[dst[i]], 1);
}

__global__ __launch_bounds__(256) void scan1_kernel(const int* __restrict__ cnt, int* __restrict__ bsum) {
  __shared__ int red[256];
  int b = blockIdx.x, t = threadIdx.x;
  int base = b * 1024 + t * 4;
  int s = 0;
  #pragma unroll
  for (int j = 0; j < 4; ++j) { if (base + j < Nn) s += cnt[base + j]; }
  red[t] = s;
  __syncthreads();
  for (int o = 128; o > 0; o >>= 1) {
    if (t < o) red[t] += red[t + o];
    __syncthreads();
  }
  if (t == 0) bsum[b] = red[0];
}

__global__ void scan2_kernel(int* __restrict__ bsum, int nb, int* __restrict__ indptr) {
  if (threadIdx.x == 0) {
    int acc = 0;
    for (int i = 0; i < nb; ++i) { int v = bsum[i]; bsum[i] = acc; acc += v; }
    indptr[Nn] = Ee;
  }
}

__global__ __launch_bounds__(256) void scan3_kernel(const int* __restrict__ cnt,
                                                    const int* __restrict__ boff,
                                                    int* __restrict__ indptr) {
  __shared__ int ls[256];
  int b = blockIdx.x, t = threadIdx.x;
  int base = b * 1024 + t * 4;
  int v[4];
  int ts = 0;
  #pragma unroll
  for (int j = 0; j < 4; ++j) { v[j] = (base + j < Nn) ? cnt[base + j] : 0; ts += v[j]; }
  ls[t] = ts;
  __syncthreads();
  for (int o = 1; o < 256; o <<= 1) {
    int x = 0;
    if (t >= o) x = ls[t - o];
    __syncthreads();
    ls[t] += x;
    __syncthreads();
  }
  int run = ls[t] - ts + boff[b];
  #pragma unroll
  for (int j = 0; j < 4; ++j) {
    if (base + j < Nn) indptr[base + j] = run;
    run += v[j];
  }
}

__global__ __launch_bounds__(256) void fill_kernel(const int* __restrict__ src, const int* __restrict__ dst,
                                                   const int* __restrict__ indptr, int* __restrict__ fillc,
                                                   int* __restrict__ adj) {
  for (int i = blockIdx.x * blockDim.x + threadIdx.x; i < Ee; i += gridDim.x * blockDim.x) {
    int d = dst[i];
    int p = atomicAdd(&fillc[d], 1);
    adj[indptr[d] + p] = src[i];
  }
}

// ---- aggregation: t = bf16((1+eps)*h + sum_{nbr} h[nbr]) ----
__global__ __launch_bounds__(256) void agg_kernel(const float* __restrict__ h, const int* __restrict__ indptr,
                                                  const int* __restrict__ adj, const float* __restrict__ epsp,
                                                  int layer, __hip_bfloat16* __restrict__ t) {
  int i = blockIdx.x * 2 + (threadIdx.x >> 7);
  if (i >= Nn) return;
  int f = threadIdx.x & 127;
  float self = h[i * Hd + f];
  float acc = 0.f;
  int s = indptr[i], e = indptr[i + 1];
  for (int p = s; p < e; ++p) acc += h[adj[p] * Hd + f];
  float val = (1.0f + epsp[layer]) * self + acc;
  t[i * Hd + f] = __float2bfloat16(val);
}

// ---- fused 2-GEMM MLP: z = relu(t@W1+b1)@W2 + b2 (bf16 MFMA 16x16x32) ----
__global__ __launch_bounds__(256) void mlp_kernel(const __hip_bfloat16* __restrict__ t,
                                                  const __hip_bfloat16* __restrict__ w1t,
                                                  const __hip_bfloat16* __restrict__ w2t,
                                                  const float* __restrict__ b1,
                                                  const float* __restrict__ b2,
                                                  float* __restrict__ z) {
  __shared__ __align__(16) unsigned char sA[32 * 1024]; // A tile, then U tile
  __shared__ __align__(16) unsigned char sW[32 * 1024]; // W1t, then W2t
  const int tid = threadIdx.x;
  const int m0 = blockIdx.x * 128;

  // stage A rows + W1t (swizzled)
  for (int c = tid; c < 2048; c += 256) {
    int row = c >> 4, bc = (c & 15) << 4;
    int so = swzb(row, bc);
    *(uint4*)(sW + so) = *(const uint4*)((const unsigned char*)w1t + row * 256 + bc);
    uint4 av = make_uint4(0u, 0u, 0u, 0u);
    int gr = m0 + row;
    if (gr < Nn) av = *(const uint4*)((const unsigned char*)t + gr * 256 + bc);
    *(uint4*)(sA + so) = av;
  }
  __syncthreads();

  const int lane = tid & 63;
  const int wave = tid >> 6;
  const int lrow = lane & 15;
  const int lkb = (lane >> 4) << 4;   // byte offset of this lane's k-octet
  const int wm = wave * 32;           // wave's 32 output rows
  const int crow = (lane >> 4) << 2;  // C/D row base

  f32x4 acc[2][8];
  #pragma unroll
  for (int a = 0; a < 2; ++a) {
    #pragma unroll
    for (int b = 0; b < 8; ++b) acc[a][b] = (f32x4){0.f, 0.f, 0.f, 0.f};
  }

  #pragma unroll
  for (int kk = 0; kk < 4; ++kk) {
    const int kb2 = kk * 64 + lkb;
    bf16x8 a0 = *(const bf16x8*)(sA + swzb(wm + lrow, kb2));
    bf16x8 a1 = *(const bf16x8*)(sA + swzb(wm + 16 + lrow, kb2));
    #pragma unroll
    for (int nf = 0; nf < 8; ++nf) {
      bf16x8 bfr = *(const bf16x8*)(sW + swzb(nf * 16 + lrow, kb2));
      acc[0][nf] = __builtin_amdgcn_mfma_f32_16x16x32_bf16(a0, bfr, acc[0][nf], 0, 0, 0);
      acc[1][nf] = __builtin_amdgcn_mfma_f32_16x16x32_bf16(a1, bfr, acc[1][nf], 0, 0, 0);
    }
  }
  __syncthreads();

  // stage W2t; write U = bf16(relu(acc + b1)) into sA (same swizzle)
  for (int c = tid; c < 2048; c += 256) {
    int row = c >> 4, bc = (c & 15) << 4;
    *(uint4*)(sW + swzb(row, bc)) = *(const uint4*)((const unsigned char*)w2t + row * 256 + bc);
  }
  #pragma unroll
  for (int nf = 0; nf < 8; ++nf) {
    const int col = nf * 16 + lrow;
    const float bb = b1[col];
    #pragma unroll
    for (int mf = 0; mf < 2; ++mf) {
      #pragma unroll
      for (int j = 0; j < 4; ++j) {
        float v = acc[mf][nf][j] + bb;
        v = v > 0.f ? v : 0.f;
        int row = wm + mf * 16 + crow + j;
        *(unsigned short*)(sA + swzb(row, col * 2)) = f2bf(v);
      }
    }
  }
  __syncthreads();

  f32x4 acc2[2][8];
  #pragma unroll
  for (int a = 0; a < 2; ++a) {
    #pragma unroll
    for (int b = 0; b < 8; ++b) acc2[a][b] = (f32x4){0.f, 0.f, 0.f, 0.f};
  }
  #pragma unroll
  for (int kk = 0; kk < 4; ++kk) {
    const int kb2 = kk * 64 + lkb;
    bf16x8 a0 = *(const bf16x8*)(sA + swzb(wm + lrow, kb2));
    bf16x8 a1 = *(const bf16x8*)(sA + swzb(wm + 16 + lrow, kb2));
    #pragma unroll
    for (int nf = 0; nf < 8; ++nf) {
      bf16x8 bfr = *(const bf16x8*)(sW + swzb(nf * 16 + lrow, kb2));
      acc2[0][nf] = __builtin_amdgcn_mfma_f32_16x16x32_bf16(a0, bfr, acc2[0][nf], 0, 0, 0);
      acc2[1][nf] = __builtin_amdgcn_mfma_f32_16x16x32_bf16(a1, bfr, acc2[1][nf], 0, 0, 0);
    }
  }

  #pragma unroll
  for (int nf = 0; nf < 8; ++nf) {
    const int col = nf * 16 + lrow;
    const float bb = b2[col];
    #pragma unroll
    for (int mf = 0; mf < 2; ++mf) {
      #pragma unroll
      for (int j = 0; j < 4; ++j) {
        int grow = m0 + wm + mf * 16 + crow + j;
        if (grow < Nn) z[grow * Hd + col] = acc2[mf][nf][j] + bb;
      }
    }
  }
}

// ---- BN stats ----
__global__ __launch_bounds__(128) void stats_kernel(const float* __restrict__ z, float* __restrict__ stats) {
  int f = threadIdx.x;
  int rs = blockIdx.x * 512;
  int re = min(rs + 512, Nn);
  float s = 0.f, q = 0.f;
  for (int i = rs; i < re; ++i) { float v = z[i * Hd + f]; s += v; q += v * v; }
  atomicAdd(&stats[f], s);
  atomicAdd(&stats[Hd + f], q);
}

__global__ __launch_bounds__(128) void bnparam_kernel(const float* __restrict__ stats,
                                                      const float* __restrict__ gammas,
                                                      const float* __restrict__ betas,
                                                      int layer, float* __restrict__ ss) {
  int f = threadIdx.x;
  const float invn = 1.0f / (float)Nn;
  float mu = stats[f] * invn;
  float var = stats[Hd + f] * invn - mu * mu;
  float sc = gammas[layer * Hd + f] * rsqrtf(var + 1e-5f);
  ss[f] = sc;
  ss[Hd + f] = betas[layer * Hd + f] - mu * sc;
}

// ---- pooling of raw x ----
__global__ __launch_bounds__(128) void pool_kernel(const float* __restrict__ v, const int* __restrict__ batch,
                                                   float* __restrict__ emb, int colOff) {
  int g = blockIdx.x / SPLIT, sp = blockIdx.x % SPLIT;
  int f = threadIdx.x;
  int lo = lower_bound_dev(batch, Nn, g);
  int hi = lower_bound_dev(batch, Nn, g + 1);
  int len = hi - lo;
  if (len <= 0) return;
  int chunk = (len + SPLIT - 1) / SPLIT;
  int rs = lo + sp * chunk;
  int re = min(rs + chunk, hi);
  if (rs >= re) return;
  float acc = 0.f;
  for (int i = rs; i < re; ++i) acc += v[i * Hd + f];
  atomicAdd(&emb[g * Din + colOff + f], acc);
}

// ---- fused BN apply + ReLU + write h + pool ----
__global__ __launch_bounds__(128) void bn_pool_kernel(const float* __restrict__ z, const float* __restrict__ ss,
                                                      const int* __restrict__ batch, float* __restrict__ h,
                                                      float* __restrict__ emb, int colOff) {
  int g = blockIdx.x / SPLIT, sp = blockIdx.x % SPLIT;
  int f = threadIdx.x;
  float sc = ss[f], sh = ss[Hd + f];
  int lo = lower_bound_dev(batch, Nn, g);
  int hi = lower_bound_dev(batch, Nn, g + 1);
  int len = hi - lo;
  if (len <= 0) return;
  int chunk = (len + SPLIT - 1) / SPLIT;
  int rs = lo + sp * chunk;
  int re = min(rs + chunk, hi);
  if (rs >= re) return;
  float acc = 0.f;
  for (int i = rs; i < re; ++i) {
    float v = z[i * Hd + f] * sc + sh;
    v = v > 0.f ? v : 0.f;
    h[i * Hd + f] = v;
    acc += v;
  }
  atomicAdd(&emb[g * Din + colOff + f], acc);
}

// ---- output head: out = emb @ Wout + bout ----
__global__ __launch_bounds__(64) void out_kernel(const float* __restrict__ emb, const float* __restrict__ Wout,
                                                 const float* __restrict__ bout, float* __restrict__ out) {
  int g = blockIdx.x;
  int lane = threadIdx.x;
  float acc[Oo];
  #pragma unroll
  for (int o = 0; o < Oo; ++o) acc[o] = 0.f;
  for (int d = lane; d < Din; d += 64) {
    float ev = emb[g * Din + d];
    #pragma unroll
    for (int o = 0; o < Oo; ++o) acc[o] += ev * Wout[d * Oo + o];
  }
  #pragma unroll
  for (int off = 32; off > 0; off >>= 1) {
    #pragma unroll
    for (int o = 0; o < Oo; ++o) acc[o] += __shfl_down(acc[o], off, 64);
  }
  if (lane == 0) {
    #pragma unroll
    for (int o = 0; o < Oo; ++o) out[g * Oo + o] = acc[o] + bout[o];
  }
}

extern "C" void kernel_launch(void* const* d_in, const int* in_sizes, int n_in,
                              void* d_out, int out_size, void* d_ws, size_t ws_size,
                              hipStream_t stream) {
  (void)in_sizes; (void)n_in; (void)out_size;
  const float* x = (const float*)d_in[0];
  const int* ei = (const int*)d_in[1];
  const int* src = ei;
  const int* dst = ei + Ee;
  const int* batch = (const int*)d_in[2];
  const float* W1s = (const float*)d_in[3];
  const float* b1s = (const float*)d_in[4];
  const float* W2s = (const float*)d_in[5];
  const float* b2s = (const float*)d_in[6];
  const float* eps = (const float*)d_in[7];
  const float* gammas = (const float*)d_in[8];
  const float* betas = (const float*)d_in[9];
  const float* Wout = (const float*)d_in[10];
  const float* bout = (const float*)d_in[11];
  float* out = (float*)d_out;

  unsigned char* ws = (unsigned char*)d_ws;
  size_t off = 0;
  auto alloc = [&](size_t bytes) -> void* {
    void* p = ws + off;
    off = (off + bytes + 255) & ~size_t(255);
    return p;
  };
  float* h = (float*)alloc((size_t)Nn * Hd * 4);
  float* z = (float*)alloc((size_t)Nn * Hd * 4);
  __hip_bfloat16* t = (__hip_bfloat16*)alloc((size_t)Nn * Hd * 2);
  int* indptr = (int*)alloc((size_t)(Nn + 1) * 4);
  int* cnt = (int*)alloc((size_t)Nn * 4);
  int* fillc = (int*)alloc((size_t)Nn * 4);
  int* adj = (int*)alloc((size_t)Ee * 4);
  int* bsum = (int*)alloc(128 * 4);
  float* emb = (float*)alloc((size_t)Gg * Din * 4);
  float* stats = (float*)alloc(256 * 4);
  float* ss = (float*)alloc(256 * 4);
  __hip_bfloat16* wt = (__hip_bfloat16*)alloc((size_t)Ll * 2 * Hd * Hd * 2);
  if (off > ws_size) return; // workspace too small -> leave output poisoned (visible failure)

  hipMemsetAsync(cnt, 0, (size_t)Nn * 4, stream);
  hipMemsetAsync(fillc, 0, (size_t)Nn * 4, stream);
  hipMemsetAsync(emb, 0, (size_t)Gg * Din * 4, stream);

  wprep_kernel<<<(Ll * 2 * Hd * Hd + 255) / 256, 256, 0, stream>>>(W1s, W2s, wt);

  count_kernel<<<2048, 256, 0, stream>>>(dst, cnt);
  const int nb = (Nn + 1023) / 1024; // 98
  scan1_kernel<<<nb, 256, 0, stream>>>(cnt, bsum);
  scan2_kernel<<<1, 64, 0, stream>>>(bsum, nb, indptr);
  scan3_kernel<<<nb, 256, 0, stream>>>(cnt, bsum, indptr);
  fill_kernel<<<2048, 256, 0, stream>>>(src, dst, indptr, fillc, adj);

  pool_kernel<<<Gg * SPLIT, 128, 0, stream>>>(x, batch, emb, 0);

  const float* hcur = x;
  for (int l = 0; l < Ll; ++l) {
    agg_kernel<<<Nn / 2, 256, 0, stream>>>(hcur, indptr, adj, eps, l, t);
    mlp_kernel<<<(Nn + 127) / 128, 256, 0, stream>>>(
        t, wt + (size_t)l * 2 * Hd * Hd, wt + (size_t)l * 2 * Hd * Hd + Hd * Hd,
        b1s + l * Hd, b2s + l * Hd, z);
    hipMemsetAsync(stats, 0, 256 * 4, stream);
    stats_kernel<<<(Nn + 511) / 512, 128, 0, stream>>>(z, stats);
    bnparam_kernel<<<1, 128, 0, stream>>>(stats, gammas, betas, l, ss);
    bn_pool_kernel<<<Gg * SPLIT, 128, 0, stream>>>(z, ss, batch, h, emb, Hd + l * Hd);
    hcur = h;
  }

  out_kernel<<<Gg, 64, 0, stream>>>(emb, Wout, bout, out);
}

// Round 2
// 731.924 us; speedup vs baseline: 2.8290x; 2.8290x over previous
//
#include <hip/hip_runtime.h>
#include <hip/hip_bf16.h>

typedef __attribute__((ext_vector_type(8))) __bf16 bf16x8;
typedef __attribute__((ext_vector_type(4))) float f32x4;
typedef unsigned short u16;
typedef unsigned int u32;

constexpr int Nn = 100000;
constexpr int Ee = 1600000;
constexpr int Hd = 128;          // F == H == 128
constexpr int Ll = 4;
constexpr int Gg = 512;
constexpr int Oo = 10;
constexpr int Din = Hd + Ll * Hd; // 640
constexpr int SPLIT = 8;
constexpr int NBLK = (Nn + 127) / 128; // 782 MLP blocks

__device__ __forceinline__ int swzb(int row, int bc) {
  // byte offset into a 128x128 bf16 tile (256 B/row), XOR-swizzled (T2, st-style)
  return (row << 8) + (bc ^ ((row & 7) << 4));
}

__device__ __forceinline__ u16 f2bf(float f) {
  __hip_bfloat16 b = __float2bfloat16(f);
  u16 u;
  __builtin_memcpy(&u, &b, 2);
  return u;
}

__device__ __forceinline__ float bf2f(u32 u) { return __uint_as_float(u << 16); }

__device__ __forceinline__ int lower_bound_dev(const int* a, int n, int key) {
  int lo = 0, hi = n;
  while (lo < hi) { int mid = (lo + hi) >> 1; if (a[mid] < key) lo = mid + 1; else hi = mid; }
  return lo;
}

// ---- x f32 -> bf16 ----
__global__ __launch_bounds__(256) void xcvt_kernel(const float* __restrict__ x, __hip_bfloat16* __restrict__ xb) {
  int i = blockIdx.x * 256 + threadIdx.x; // unit of 8 elements
  const int total = Nn * Hd / 8;
  if (i >= total) return;
  f32x4 v0 = *(const f32x4*)(x + (size_t)i * 8);
  f32x4 v1 = *(const f32x4*)(x + (size_t)i * 8 + 4);
  uint4 o;
  o.x = (u32)f2bf(v0[0]) | ((u32)f2bf(v0[1]) << 16);
  o.y = (u32)f2bf(v0[2]) | ((u32)f2bf(v0[3]) << 16);
  o.z = (u32)f2bf(v1[0]) | ((u32)f2bf(v1[1]) << 16);
  o.w = (u32)f2bf(v1[2]) | ((u32)f2bf(v1[3]) << 16);
  *(uint4*)((u16*)xb + (size_t)i * 8) = o;
}

// ---- weight prep: W1s/W2s f32 [l][k][n] -> wt bf16 [l][w][n][k] (transposed) ----
__global__ __launch_bounds__(256) void wprep_kernel(const float* __restrict__ W1s,
                                                    const float* __restrict__ W2s,
                                                    __hip_bfloat16* __restrict__ wt) {
  int idx = blockIdx.x * 256 + threadIdx.x;
  if (idx >= Ll * 2 * Hd * Hd) return;
  int l = idx >> 15;
  int w = (idx >> 14) & 1;
  int nn = (idx >> 7) & 127;
  int k = idx & 127;
  const float* W = w ? W2s : W1s;
  wt[idx] = __float2bfloat16(W[l * Hd * Hd + k * Hd + nn]);
}

// ---- CSR build ----
__global__ __launch_bounds__(256) void count_kernel(const int* __restrict__ dst, int* __restrict__ cnt) {
  for (int i = blockIdx.x * blockDim.x + threadIdx.x; i < Ee; i += gridDim.x * blockDim.x)
    atomicAdd(&cnt[dst[i]], 1);
}

__global__ __launch_bounds__(256) void scan1_kernel(const int* __restrict__ cnt, int* __restrict__ bsum) {
  __shared__ int red[256];
  int b = blockIdx.x, t = threadIdx.x;
  int base = b * 1024 + t * 4;
  int s = 0;
  #pragma unroll
  for (int j = 0; j < 4; ++j) { if (base + j < Nn) s += cnt[base + j]; }
  red[t] = s;
  __syncthreads();
  for (int o = 128; o > 0; o >>= 1) {
    if (t < o) red[t] += red[t + o];
    __syncthreads();
  }
  if (t == 0) bsum[b] = red[0];
}

__global__ void scan2_kernel(int* __restrict__ bsum, int nb, int* __restrict__ indptr) {
  if (threadIdx.x == 0) {
    int acc = 0;
    for (int i = 0; i < nb; ++i) { int v = bsum[i]; bsum[i] = acc; acc += v; }
    indptr[Nn] = Ee;
  }
}

__global__ __launch_bounds__(256) void scan3_kernel(const int* __restrict__ cnt,
                                                    const int* __restrict__ boff,
                                                    int* __restrict__ indptr) {
  __shared__ int ls[256];
  int b = blockIdx.x, t = threadIdx.x;
  int base = b * 1024 + t * 4;
  int v[4];
  int ts = 0;
  #pragma unroll
  for (int j = 0; j < 4; ++j) { v[j] = (base + j < Nn) ? cnt[base + j] : 0; ts += v[j]; }
  ls[t] = ts;
  __syncthreads();
  for (int o = 1; o < 256; o <<= 1) {
    int x = 0;
    if (t >= o) x = ls[t - o];
    __syncthreads();
    ls[t] += x;
    __syncthreads();
  }
  int run = ls[t] - ts + boff[b];
  #pragma unroll
  for (int j = 0; j < 4; ++j) {
    if (base + j < Nn) indptr[base + j] = run;
    run += v[j];
  }
}

__global__ __launch_bounds__(256) void fill_kernel(const int* __restrict__ src, const int* __restrict__ dst,
                                                   const int* __restrict__ indptr, int* __restrict__ fillc,
                                                   int* __restrict__ adj) {
  for (int i = blockIdx.x * blockDim.x + threadIdx.x; i < Ee; i += gridDim.x * blockDim.x) {
    int d = dst[i];
    int p = atomicAdd(&fillc[d], 1);
    adj[indptr[d] + p] = src[i];
  }
}

// ---- aggregation: t = bf16((1+eps)*h + sum_{nbr} h[nbr]); one wave per node ----
__global__ __launch_bounds__(256) void agg_kernel(const __hip_bfloat16* __restrict__ hb,
                                                  const int* __restrict__ indptr,
                                                  const int* __restrict__ adj,
                                                  const float* __restrict__ epsp,
                                                  int layer, __hip_bfloat16* __restrict__ t) {
  int wid = blockIdx.x * 4 + (threadIdx.x >> 6); // node
  if (wid >= Nn) return;
  int lane = threadIdx.x & 63;
  int cb = lane * 2; // feature pair base
  const u16* hp = (const u16*)hb;
  u32 selfu = *(const u32*)(hp + (size_t)wid * Hd + cb);
  float eps1 = 1.0f + epsp[layer];
  int s = __builtin_amdgcn_readfirstlane(indptr[wid]);
  int e = __builtin_amdgcn_readfirstlane(indptr[wid + 1]);
  float a0 = 0.f, a1 = 0.f;
  int p = s;
  for (; p + 2 <= e; p += 2) {
    int n0 = adj[p], n1 = adj[p + 1];
    u32 v0 = *(const u32*)(hp + (size_t)n0 * Hd + cb);
    u32 v1 = *(const u32*)(hp + (size_t)n1 * Hd + cb);
    a0 += bf2f(v0 & 0xffffu) + bf2f(v1 & 0xffffu);
    a1 += bf2f(v0 >> 16) + bf2f(v1 >> 16);
  }
  if (p < e) {
    u32 v0 = *(const u32*)(hp + (size_t)adj[p] * Hd + cb);
    a0 += bf2f(v0 & 0xffffu);
    a1 += bf2f(v0 >> 16);
  }
  a0 += eps1 * bf2f(selfu & 0xffffu);
  a1 += eps1 * bf2f(selfu >> 16);
  u32 outv = (u32)f2bf(a0) | ((u32)f2bf(a1) << 16);
  *(u32*)((u16*)t + (size_t)wid * Hd + cb) = outv;
}

// ---- fused 2-GEMM MLP + BN partial stats: z = relu(t@W1+b1)@W2 + b2 ----
__global__ __launch_bounds__(256) void mlp_kernel(const __hip_bfloat16* __restrict__ t,
                                                  const __hip_bfloat16* __restrict__ w1t,
                                                  const __hip_bfloat16* __restrict__ w2t,
                                                  const float* __restrict__ b1,
                                                  const float* __restrict__ b2,
                                                  __hip_bfloat16* __restrict__ z,
                                                  float* __restrict__ pstats) {
  __shared__ __align__(16) unsigned char sA[32 * 1024]; // A tile, then U tile
  __shared__ __align__(16) unsigned char sW[32 * 1024]; // W1t, then W2t
  const int tid = threadIdx.x;
  const int m0 = blockIdx.x * 128;

  // stage A rows + W1t (swizzled)
  for (int c = tid; c < 2048; c += 256) {
    int row = c >> 4, bc = (c & 15) << 4;
    int so = swzb(row, bc);
    *(uint4*)(sW + so) = *(const uint4*)((const unsigned char*)w1t + row * 256 + bc);
    uint4 av = make_uint4(0u, 0u, 0u, 0u);
    int gr = m0 + row;
    if (gr < Nn) av = *(const uint4*)((const unsigned char*)t + (size_t)gr * 256 + bc);
    *(uint4*)(sA + so) = av;
  }
  __syncthreads();

  const int lane = tid & 63;
  const int wave = tid >> 6;
  const int lrow = lane & 15;
  const int lkb = (lane >> 4) << 4;   // byte offset of this lane's k-octet
  const int wm = wave * 32;           // wave's 32 output rows
  const int crow = (lane >> 4) << 2;  // C/D row base

  f32x4 acc[2][8];
  #pragma unroll
  for (int a = 0; a < 2; ++a) {
    #pragma unroll
    for (int b = 0; b < 8; ++b) acc[a][b] = (f32x4){0.f, 0.f, 0.f, 0.f};
  }

  #pragma unroll
  for (int kk = 0; kk < 4; ++kk) {
    const int kb2 = kk * 64 + lkb;
    bf16x8 a0 = *(const bf16x8*)(sA + swzb(wm + lrow, kb2));
    bf16x8 a1 = *(const bf16x8*)(sA + swzb(wm + 16 + lrow, kb2));
    #pragma unroll
    for (int nf = 0; nf < 8; ++nf) {
      bf16x8 bfr = *(const bf16x8*)(sW + swzb(nf * 16 + lrow, kb2));
      acc[0][nf] = __builtin_amdgcn_mfma_f32_16x16x32_bf16(a0, bfr, acc[0][nf], 0, 0, 0);
      acc[1][nf] = __builtin_amdgcn_mfma_f32_16x16x32_bf16(a1, bfr, acc[1][nf], 0, 0, 0);
    }
  }
  __syncthreads();

  // stage W2t; write U = bf16(relu(acc + b1)) into sA (same swizzle)
  for (int c = tid; c < 2048; c += 256) {
    int row = c >> 4, bc = (c & 15) << 4;
    *(uint4*)(sW + swzb(row, bc)) = *(const uint4*)((const unsigned char*)w2t + row * 256 + bc);
  }
  #pragma unroll
  for (int nf = 0; nf < 8; ++nf) {
    const int col = nf * 16 + lrow;
    const float bb = b1[col];
    #pragma unroll
    for (int mf = 0; mf < 2; ++mf) {
      #pragma unroll
      for (int j = 0; j < 4; ++j) {
        float v = acc[mf][nf][j] + bb;
        v = v > 0.f ? v : 0.f;
        int row = wm + mf * 16 + crow + j;
        *(u16*)(sA + swzb(row, col * 2)) = f2bf(v);
      }
    }
  }
  __syncthreads();

  f32x4 acc2[2][8];
  #pragma unroll
  for (int a = 0; a < 2; ++a) {
    #pragma unroll
    for (int b = 0; b < 8; ++b) acc2[a][b] = (f32x4){0.f, 0.f, 0.f, 0.f};
  }
  #pragma unroll
  for (int kk = 0; kk < 4; ++kk) {
    const int kb2 = kk * 64 + lkb;
    bf16x8 a0 = *(const bf16x8*)(sA + swzb(wm + lrow, kb2));
    bf16x8 a1 = *(const bf16x8*)(sA + swzb(wm + 16 + lrow, kb2));
    #pragma unroll
    for (int nf = 0; nf < 8; ++nf) {
      bf16x8 bfr = *(const bf16x8*)(sW + swzb(nf * 16 + lrow, kb2));
      acc2[0][nf] = __builtin_amdgcn_mfma_f32_16x16x32_bf16(a0, bfr, acc2[0][nf], 0, 0, 0);
      acc2[1][nf] = __builtin_amdgcn_mfma_f32_16x16x32_bf16(a1, bfr, acc2[1][nf], 0, 0, 0);
    }
  }
  __syncthreads(); // done reading sA/sW; reuse for stats reduce

  float* sred = (float*)sA;          // [4][128]
  float* qred = (float*)(sA + 2048); // [4][128]
  u16* zp = (u16*)z;
  #pragma unroll
  for (int nf = 0; nf < 8; ++nf) {
    const int col = nf * 16 + lrow;
    const float bb = b2[col];
    float s = 0.f, q = 0.f;
    #pragma unroll
    for (int mf = 0; mf < 2; ++mf) {
      #pragma unroll
      for (int j = 0; j < 4; ++j) {
        int grow = m0 + wm + mf * 16 + crow + j;
        if (grow < Nn) {
          float v = acc2[mf][nf][j] + bb;
          zp[(size_t)grow * Hd + col] = f2bf(v);
          s += v; q += v * v;
        }
      }
    }
    s += __shfl_xor(s, 16, 64); s += __shfl_xor(s, 32, 64);
    q += __shfl_xor(q, 16, 64); q += __shfl_xor(q, 32, 64);
    if (lane < 16) { sred[wave * 128 + col] = s; qred[wave * 128 + col] = q; }
  }
  __syncthreads();
  if (tid < 128) {
    float a = sred[tid] + sred[128 + tid] + sred[256 + tid] + sred[384 + tid];
    pstats[(size_t)blockIdx.x * 256 + tid] = a;
  } else {
    int c = tid - 128;
    float a = qred[c] + qred[128 + c] + qred[256 + c] + qred[384 + c];
    pstats[(size_t)blockIdx.x * 256 + tid] = a;
  }
}

// ---- reduce per-block stats partials ----
__global__ __launch_bounds__(256) void redstats_kernel(const float* __restrict__ pstats,
                                                       float* __restrict__ stats) {
  __shared__ float red[256];
  int slot = blockIdx.x, t = threadIdx.x;
  float a = 0.f;
  for (int i = t; i < NBLK; i += 256) a += pstats[(size_t)i * 256 + slot];
  red[t] = a;
  __syncthreads();
  for (int o = 128; o > 0; o >>= 1) {
    if (t < o) red[t] += red[t + o];
    __syncthreads();
  }
  if (t == 0) stats[slot] = red[0];
}

__global__ __launch_bounds__(128) void bnparam_kernel(const float* __restrict__ stats,
                                                      const float* __restrict__ gammas,
                                                      const float* __restrict__ betas,
                                                      int layer, float* __restrict__ ss) {
  int f = threadIdx.x;
  const float invn = 1.0f / (float)Nn;
  float mu = stats[f] * invn;
  float var = stats[Hd + f] * invn - mu * mu;
  float sc = gammas[layer * Hd + f] * rsqrtf(var + 1e-5f);
  ss[f] = sc;
  ss[Hd + f] = betas[layer * Hd + f] - mu * sc;
}

// ---- pooling of raw x (f32) ----
__global__ __launch_bounds__(128) void pool_kernel(const float* __restrict__ v, const int* __restrict__ batch,
                                                   float* __restrict__ emb, int colOff) {
  int g = blockIdx.x / SPLIT, sp = blockIdx.x % SPLIT;
  int f = threadIdx.x;
  int lo = lower_bound_dev(batch, Nn, g);
  int hi = lower_bound_dev(batch, Nn, g + 1);
  int len = hi - lo;
  if (len <= 0) return;
  int chunk = (len + SPLIT - 1) / SPLIT;
  int rs = lo + sp * chunk;
  int re = min(rs + chunk, hi);
  if (rs >= re) return;
  float acc = 0.f;
  for (int i = rs; i < re; ++i) acc += v[(size_t)i * Hd + f];
  atomicAdd(&emb[g * Din + colOff + f], acc);
}

// ---- fused BN apply + ReLU + write h (bf16) + pool ----
__global__ __launch_bounds__(128) void bn_pool_kernel(const __hip_bfloat16* __restrict__ z,
                                                      const float* __restrict__ ss,
                                                      const int* __restrict__ batch,
                                                      __hip_bfloat16* __restrict__ h,
                                                      float* __restrict__ emb, int colOff) {
  int g = blockIdx.x / SPLIT, sp = blockIdx.x % SPLIT;
  int c2 = (threadIdx.x & 63) * 2; // feature pair
  int rh = threadIdx.x >> 6;
  float sc0 = ss[c2], sh0 = ss[Hd + c2];
  float sc1 = ss[c2 + 1], sh1 = ss[Hd + c2 + 1];
  int lo = lower_bound_dev(batch, Nn, g);
  int hi = lower_bound_dev(batch, Nn, g + 1);
  int len = hi - lo;
  if (len <= 0) return;
  int chunk = (len + SPLIT - 1) / SPLIT;
  int rs = lo + sp * chunk;
  int re = min(rs + chunk, hi);
  if (rs >= re) return;
  const u16* zp = (const u16*)z;
  u16* hp = (u16*)h;
  float a0 = 0.f, a1 = 0.f;
  for (int i = rs + rh; i < re; i += 2) {
    u32 v = *(const u32*)(zp + (size_t)i * Hd + c2);
    float v0 = bf2f(v & 0xffffu) * sc0 + sh0; v0 = fmaxf(v0, 0.f);
    float v1 = bf2f(v >> 16) * sc1 + sh1; v1 = fmaxf(v1, 0.f);
    *(u32*)(hp + (size_t)i * Hd + c2) = (u32)f2bf(v0) | ((u32)f2bf(v1) << 16);
    a0 += v0; a1 += v1;
  }
  atomicAdd(&emb[g * Din + colOff + c2], a0);
  atomicAdd(&emb[g * Din + colOff + c2 + 1], a1);
}

// ---- output head: out = emb @ Wout + bout ----
__global__ __launch_bounds__(64) void out_kernel(const float* __restrict__ emb, const float* __restrict__ Wout,
                                                 const float* __restrict__ bout, float* __restrict__ out) {
  int g = blockIdx.x;
  int lane = threadIdx.x;
  float acc[Oo];
  #pragma unroll
  for (int o = 0; o < Oo; ++o) acc[o] = 0.f;
  for (int d = lane; d < Din; d += 64) {
    float ev = emb[g * Din + d];
    #pragma unroll
    for (int o = 0; o < Oo; ++o) acc[o] += ev * Wout[d * Oo + o];
  }
  #pragma unroll
  for (int off = 32; off > 0; off >>= 1) {
    #pragma unroll
    for (int o = 0; o < Oo; ++o) acc[o] += __shfl_down(acc[o], off, 64);
  }
  if (lane == 0) {
    #pragma unroll
    for (int o = 0; o < Oo; ++o) out[g * Oo + o] = acc[o] + bout[o];
  }
}

extern "C" void kernel_launch(void* const* d_in, const int* in_sizes, int n_in,
                              void* d_out, int out_size, void* d_ws, size_t ws_size,
                              hipStream_t stream) {
  (void)in_sizes; (void)n_in; (void)out_size;
  const float* x = (const float*)d_in[0];
  const int* ei = (const int*)d_in[1];
  const int* src = ei;
  const int* dst = ei + Ee;
  const int* batch = (const int*)d_in[2];
  const float* W1s = (const float*)d_in[3];
  const float* b1s = (const float*)d_in[4];
  const float* W2s = (const float*)d_in[5];
  const float* b2s = (const float*)d_in[6];
  const float* eps = (const float*)d_in[7];
  const float* gammas = (const float*)d_in[8];
  const float* betas = (const float*)d_in[9];
  const float* Wout = (const float*)d_in[10];
  const float* bout = (const float*)d_in[11];
  float* out = (float*)d_out;

  unsigned char* ws = (unsigned char*)d_ws;
  size_t off = 0;
  auto alloc = [&](size_t bytes) -> void* {
    void* p = ws + off;
    off = (off + bytes + 255) & ~size_t(255);
    return p;
  };
  __hip_bfloat16* xb = (__hip_bfloat16*)alloc((size_t)Nn * Hd * 2);
  __hip_bfloat16* h = (__hip_bfloat16*)alloc((size_t)Nn * Hd * 2);
  __hip_bfloat16* z = (__hip_bfloat16*)alloc((size_t)Nn * Hd * 2);
  __hip_bfloat16* t = (__hip_bfloat16*)alloc((size_t)Nn * Hd * 2);
  int* indptr = (int*)alloc((size_t)(Nn + 1) * 4);
  int* cnt = (int*)alloc((size_t)Nn * 4);
  int* fillc = (int*)alloc((size_t)Nn * 4);
  int* adj = (int*)alloc((size_t)Ee * 4);
  int* bsum = (int*)alloc(128 * 4);
  float* emb = (float*)alloc((size_t)Gg * Din * 4);
  float* pstats = (float*)alloc((size_t)NBLK * 256 * 4);
  float* stats = (float*)alloc(256 * 4);
  float* ss = (float*)alloc(256 * 4);
  __hip_bfloat16* wt = (__hip_bfloat16*)alloc((size_t)Ll * 2 * Hd * Hd * 2);
  if (off > ws_size) return; // workspace too small -> leave output poisoned (visible failure)

  hipMemsetAsync(cnt, 0, (size_t)Nn * 4, stream);
  hipMemsetAsync(fillc, 0, (size_t)Nn * 4, stream);
  hipMemsetAsync(emb, 0, (size_t)Gg * Din * 4, stream);

  xcvt_kernel<<<(Nn * Hd / 8 + 255) / 256, 256, 0, stream>>>(x, xb);
  wprep_kernel<<<(Ll * 2 * Hd * Hd + 255) / 256, 256, 0, stream>>>(W1s, W2s, wt);

  count_kernel<<<2048, 256, 0, stream>>>(dst, cnt);
  const int nb = (Nn + 1023) / 1024; // 98
  scan1_kernel<<<nb, 256, 0, stream>>>(cnt, bsum);
  scan2_kernel<<<1, 64, 0, stream>>>(bsum, nb, indptr);
  scan3_kernel<<<nb, 256, 0, stream>>>(cnt, bsum, indptr);
  fill_kernel<<<2048, 256, 0, stream>>>(src, dst, indptr, fillc, adj);

  pool_kernel<<<Gg * SPLIT, 128, 0, stream>>>(x, batch, emb, 0);

  const __hip_bfloat16* hcur = xb;
  for (int l = 0; l < Ll; ++l) {
    agg_kernel<<<(Nn + 3) / 4, 256, 0, stream>>>(hcur, indptr, adj, eps, l, t);
    mlp_kernel<<<NBLK, 256, 0, stream>>>(
        t, wt + (size_t)l * 2 * Hd * Hd, wt + (size_t)l * 2 * Hd * Hd + Hd * Hd,
        b1s + l * Hd, b2s + l * Hd, z, pstats);
    redstats_kernel<<<256, 256, 0, stream>>>(pstats, stats);
    bnparam_kernel<<<1, 128, 0, stream>>>(stats, gammas, betas, l, ss);
    bn_pool_kernel<<<Gg * SPLIT, 128, 0, stream>>>(z, ss, batch, h, emb, Hd + l * Hd);
    hcur = h;
  }

  out_kernel<<<Gg, 64, 0, stream>>>(emb, Wout, bout, out);
}

// Round 3
// 601.728 us; speedup vs baseline: 3.4411x; 1.2164x over previous
//
#include <hip/hip_runtime.h>
#include <hip/hip_bf16.h>

typedef __attribute__((ext_vector_type(8))) __bf16 bf16x8;
typedef __attribute__((ext_vector_type(4))) float f32x4;
typedef unsigned short u16;
typedef unsigned int u32;

constexpr int Nn = 100000;
constexpr int Ee = 1600000;
constexpr int Hd = 128;          // F == H == 128
constexpr int Ll = 4;
constexpr int Gg = 512;
constexpr int Oo = 10;
constexpr int Din = Hd + Ll * Hd; // 640
constexpr int SPLIT = 8;
constexpr int NBLK = (Nn + 127) / 128; // 782 MLP tiles

// ---- bucketed CSR build params ----
constexpr int NB = 256;               // buckets
constexpr int NPB = 392;              // nodes per bucket (256*392 = 100352 >= Nn)
constexpr int BCAP = 8192;            // bucket capacity (avg 6250, +24 sigma safe)
constexpr int BATCH = 8192;           // edges per binA block
constexpr int NBATCH = (Ee + BATCH - 1) / BATCH; // 196

__device__ __forceinline__ int swzb(int row, int bc) {
  // byte offset into a 128x128 bf16 tile (256 B/row), XOR-swizzled (T2, st-style)
  return (row << 8) + (bc ^ ((row & 7) << 4));
}

__device__ __forceinline__ u16 f2bf(float f) {
  __hip_bfloat16 b = __float2bfloat16(f);
  u16 u;
  __builtin_memcpy(&u, &b, 2);
  return u;
}

__device__ __forceinline__ float bf2f(u32 u) { return __uint_as_float(u << 16); }

__device__ __forceinline__ int lower_bound_dev(const int* a, int n, int key) {
  int lo = 0, hi = n;
  while (lo < hi) { int mid = (lo + hi) >> 1; if (a[mid] < key) lo = mid + 1; else hi = mid; }
  return lo;
}

// ---- x f32 -> bf16 ----
__global__ __launch_bounds__(256) void xcvt_kernel(const float* __restrict__ x, __hip_bfloat16* __restrict__ xb) {
  int i = blockIdx.x * 256 + threadIdx.x; // unit of 8 elements
  const int total = Nn * Hd / 8;
  if (i >= total) return;
  f32x4 v0 = *(const f32x4*)(x + (size_t)i * 8);
  f32x4 v1 = *(const f32x4*)(x + (size_t)i * 8 + 4);
  uint4 o;
  o.x = (u32)f2bf(v0[0]) | ((u32)f2bf(v0[1]) << 16);
  o.y = (u32)f2bf(v0[2]) | ((u32)f2bf(v0[3]) << 16);
  o.z = (u32)f2bf(v1[0]) | ((u32)f2bf(v1[1]) << 16);
  o.w = (u32)f2bf(v1[2]) | ((u32)f2bf(v1[3]) << 16);
  *(uint4*)((u16*)xb + (size_t)i * 8) = o;
}

// ---- weight prep: W1s/W2s f32 [l][k][n] -> wt bf16 [l][w][n][k] (transposed) ----
__global__ __launch_bounds__(256) void wprep_kernel(const float* __restrict__ W1s,
                                                    const float* __restrict__ W2s,
                                                    __hip_bfloat16* __restrict__ wt) {
  int idx = blockIdx.x * 256 + threadIdx.x;
  if (idx >= Ll * 2 * Hd * Hd) return;
  int l = idx >> 15;
  int w = (idx >> 14) & 1;
  int nn = (idx >> 7) & 127;
  int k = idx & 127;
  const float* W = w ? W2s : W1s;
  wt[idx] = __float2bfloat16(W[l * Hd * Hd + k * Hd + nn]);
}

// ---- bucketed CSR build ----
__global__ void initgptr_kernel(int* __restrict__ gptr) {
  int i = threadIdx.x;
  if (i < NB) gptr[i] = i * BCAP;
}

// Phase A: bin edges by dst-bucket with LDS reorder so global writes are coalesced
__global__ __launch_bounds__(256) void binA_kernel(const int* __restrict__ src, const int* __restrict__ dst,
                                                   int* __restrict__ gptr, u32* __restrict__ buckets) {
  __shared__ int hist[NB];
  __shared__ int lbase[NB];
  __shared__ int lpos[NB];
  __shared__ int gbaseS[NB];
  __shared__ int scanT[NB];
  __shared__ u32 reorder[BATCH];
  const int tid = threadIdx.x;
  const int e0 = blockIdx.x * BATCH;
  const int n = min(BATCH, Ee - e0);

  hist[tid] = 0;
  __syncthreads();
  for (int k = tid; k < n; k += 256) {
    int d = dst[e0 + k];
    atomicAdd(&hist[d / NPB], 1);
  }
  __syncthreads();
  // exclusive scan hist -> lbase
  int v = hist[tid];
  scanT[tid] = v;
  __syncthreads();
  for (int off = 1; off < NB; off <<= 1) {
    int x = (tid >= off) ? scanT[tid - off] : 0;
    __syncthreads();
    scanT[tid] += x;
    __syncthreads();
  }
  lbase[tid] = scanT[tid] - v;
  lpos[tid] = 0;
  __syncthreads();
  // reorder into bucket-grouped LDS
  for (int k = tid; k < n; k += 256) {
    int d = dst[e0 + k];
    int s = src[e0 + k];
    int b = d / NPB;
    int dlo = d - b * NPB;
    int p = lbase[b] + atomicAdd(&lpos[b], 1);
    reorder[p] = ((u32)dlo << 17) | (u32)s;
  }
  __syncthreads();
  // claim global ranges
  if (hist[tid] > 0) gbaseS[tid] = atomicAdd(&gptr[tid], hist[tid]);
  __syncthreads();
  // flat coalesced flush (binary search bucket per position)
  for (int p = tid; p < n; p += 256) {
    int lo = 0, hi = NB - 1;
    while (lo < hi) { int mid = (lo + hi + 1) >> 1; if (lbase[mid] <= p) lo = mid; else hi = mid - 1; }
    buckets[gbaseS[lo] + (p - lbase[lo])] = reorder[p];
  }
}

// tiny scan over bucket counts -> adj bases; also terminator of indptr
__global__ __launch_bounds__(256) void bucketscan_kernel(const int* __restrict__ gptr,
                                                         int* __restrict__ bmeta,
                                                         int* __restrict__ indptr) {
  __shared__ int sc[NB];
  int tid = threadIdx.x;
  int cnt = gptr[tid] - tid * BCAP;
  sc[tid] = cnt;
  __syncthreads();
  for (int off = 1; off < NB; off <<= 1) {
    int x = (tid >= off) ? sc[tid - off] : 0;
    __syncthreads();
    sc[tid] += x;
    __syncthreads();
  }
  bmeta[tid] = cnt;
  bmeta[NB + tid] = sc[tid] - cnt; // exclusive = adj base
  if (tid == 0) indptr[Nn] = Ee;
}

// Phase B: per-bucket node histogram + placement (block-local scatter window)
__global__ __launch_bounds__(512) void place_kernel(const u32* __restrict__ buckets,
                                                    const int* __restrict__ bmeta,
                                                    int* __restrict__ indptr, int* __restrict__ adj) {
  __shared__ int ncnt[512];
  __shared__ int nofs[NPB];
  __shared__ int lcur[NPB];
  const int tid = threadIdx.x;
  const int b = blockIdx.x;
  const int cnt = bmeta[b];
  const int adjbase = bmeta[NB + b];
  const int ebase = b * BCAP;
  const int node0 = b * NPB;
  const int nnodes = min(NPB, Nn - node0);

  ncnt[tid] = 0;
  if (tid < NPB) lcur[tid] = 0;
  __syncthreads();
  for (int k = tid; k < cnt; k += 512) atomicAdd(&ncnt[buckets[ebase + k] >> 17], 1);
  __syncthreads();
  int v = ncnt[tid];
  for (int off = 1; off < 512; off <<= 1) {
    int x = (tid >= off) ? ncnt[tid - off] : 0;
    __syncthreads();
    ncnt[tid] += x;
    __syncthreads();
  }
  if (tid < NPB) nofs[tid] = ncnt[tid] - v;
  __syncthreads();
  if (tid < nnodes) indptr[node0 + tid] = adjbase + nofs[tid];
  for (int k = tid; k < cnt; k += 512) {
    u32 u = buckets[ebase + k];
    int dlo = u >> 17;
    int s = (int)(u & 0x1FFFFu);
    int p = atomicAdd(&lcur[dlo], 1);
    adj[adjbase + nofs[dlo] + p] = s;
  }
}

// ---- aggregation: t = bf16((1+eps)*h + sum_{nbr} h[nbr]); one wave per node ----
__global__ __launch_bounds__(256) void agg_kernel(const __hip_bfloat16* __restrict__ hb,
                                                  const int* __restrict__ indptr,
                                                  const int* __restrict__ adj,
                                                  const float* __restrict__ epsp,
                                                  int layer, __hip_bfloat16* __restrict__ t) {
  int wid = blockIdx.x * 4 + (threadIdx.x >> 6); // node
  if (wid >= Nn) return;
  int lane = threadIdx.x & 63;
  int cb = lane * 2; // feature pair base
  const u16* hp = (const u16*)hb;
  u32 selfu = *(const u32*)(hp + (size_t)wid * Hd + cb);
  float eps1 = 1.0f + epsp[layer];
  int s = __builtin_amdgcn_readfirstlane(indptr[wid]);
  int e = __builtin_amdgcn_readfirstlane(indptr[wid + 1]);
  float a0 = 0.f, a1 = 0.f;
  int p = s;
  for (; p + 4 <= e; p += 4) {
    int n0 = adj[p], n1 = adj[p + 1], n2 = adj[p + 2], n3 = adj[p + 3];
    u32 v0 = *(const u32*)(hp + (size_t)n0 * Hd + cb);
    u32 v1 = *(const u32*)(hp + (size_t)n1 * Hd + cb);
    u32 v2 = *(const u32*)(hp + (size_t)n2 * Hd + cb);
    u32 v3 = *(const u32*)(hp + (size_t)n3 * Hd + cb);
    a0 += bf2f(v0 & 0xffffu) + bf2f(v1 & 0xffffu) + bf2f(v2 & 0xffffu) + bf2f(v3 & 0xffffu);
    a1 += bf2f(v0 >> 16) + bf2f(v1 >> 16) + bf2f(v2 >> 16) + bf2f(v3 >> 16);
  }
  for (; p < e; ++p) {
    u32 v0 = *(const u32*)(hp + (size_t)adj[p] * Hd + cb);
    a0 += bf2f(v0 & 0xffffu);
    a1 += bf2f(v0 >> 16);
  }
  a0 += eps1 * bf2f(selfu & 0xffffu);
  a1 += eps1 * bf2f(selfu >> 16);
  u32 outv = (u32)f2bf(a0) | ((u32)f2bf(a1) << 16);
  *(u32*)((u16*)t + (size_t)wid * Hd + cb) = outv;
}

// ---- fused 2-GEMM MLP + BN partial stats: z = relu(t@W1+b1)@W2 + b2 ----
__global__ __launch_bounds__(256) void mlp_kernel(const __hip_bfloat16* __restrict__ t,
                                                  const __hip_bfloat16* __restrict__ w1t,
                                                  const __hip_bfloat16* __restrict__ w2t,
                                                  const float* __restrict__ b1,
                                                  const float* __restrict__ b2,
                                                  __hip_bfloat16* __restrict__ z,
                                                  float* __restrict__ pstats) {
  __shared__ __align__(16) unsigned char sA[32 * 1024]; // A tile, then U tile
  __shared__ __align__(16) unsigned char sW[32 * 1024]; // W1t, then W2t
  const int tid = threadIdx.x;
  const int m0 = blockIdx.x * 128;

  // stage A rows + W1t (swizzled)
  for (int c = tid; c < 2048; c += 256) {
    int row = c >> 4, bc = (c & 15) << 4;
    int so = swzb(row, bc);
    *(uint4*)(sW + so) = *(const uint4*)((const unsigned char*)w1t + row * 256 + bc);
    uint4 av = make_uint4(0u, 0u, 0u, 0u);
    int gr = m0 + row;
    if (gr < Nn) av = *(const uint4*)((const unsigned char*)t + (size_t)gr * 256 + bc);
    *(uint4*)(sA + so) = av;
  }
  __syncthreads();

  const int lane = tid & 63;
  const int wave = tid >> 6;
  const int lrow = lane & 15;
  const int lkb = (lane >> 4) << 4;   // byte offset of this lane's k-octet
  const int wm = wave * 32;           // wave's 32 output rows
  const int crow = (lane >> 4) << 2;  // C/D row base

  f32x4 acc[2][8];
  #pragma unroll
  for (int a = 0; a < 2; ++a) {
    #pragma unroll
    for (int b = 0; b < 8; ++b) acc[a][b] = (f32x4){0.f, 0.f, 0.f, 0.f};
  }

  #pragma unroll
  for (int kk = 0; kk < 4; ++kk) {
    const int kb2 = kk * 64 + lkb;
    bf16x8 a0 = *(const bf16x8*)(sA + swzb(wm + lrow, kb2));
    bf16x8 a1 = *(const bf16x8*)(sA + swzb(wm + 16 + lrow, kb2));
    #pragma unroll
    for (int nf = 0; nf < 8; ++nf) {
      bf16x8 bfr = *(const bf16x8*)(sW + swzb(nf * 16 + lrow, kb2));
      acc[0][nf] = __builtin_amdgcn_mfma_f32_16x16x32_bf16(a0, bfr, acc[0][nf], 0, 0, 0);
      acc[1][nf] = __builtin_amdgcn_mfma_f32_16x16x32_bf16(a1, bfr, acc[1][nf], 0, 0, 0);
    }
  }
  __syncthreads();

  // stage W2t; write U = bf16(relu(acc + b1)) into sA (same swizzle)
  for (int c = tid; c < 2048; c += 256) {
    int row = c >> 4, bc = (c & 15) << 4;
    *(uint4*)(sW + swzb(row, bc)) = *(const uint4*)((const unsigned char*)w2t + row * 256 + bc);
  }
  #pragma unroll
  for (int nf = 0; nf < 8; ++nf) {
    const int col = nf * 16 + lrow;
    const float bb = b1[col];
    #pragma unroll
    for (int mf = 0; mf < 2; ++mf) {
      #pragma unroll
      for (int j = 0; j < 4; ++j) {
        float v = acc[mf][nf][j] + bb;
        v = v > 0.f ? v : 0.f;
        int row = wm + mf * 16 + crow + j;
        *(u16*)(sA + swzb(row, col * 2)) = f2bf(v);
      }
    }
  }
  __syncthreads();

  f32x4 acc2[2][8];
  #pragma unroll
  for (int a = 0; a < 2; ++a) {
    #pragma unroll
    for (int b = 0; b < 8; ++b) acc2[a][b] = (f32x4){0.f, 0.f, 0.f, 0.f};
  }
  #pragma unroll
  for (int kk = 0; kk < 4; ++kk) {
    const int kb2 = kk * 64 + lkb;
    bf16x8 a0 = *(const bf16x8*)(sA + swzb(wm + lrow, kb2));
    bf16x8 a1 = *(const bf16x8*)(sA + swzb(wm + 16 + lrow, kb2));
    #pragma unroll
    for (int nf = 0; nf < 8; ++nf) {
      bf16x8 bfr = *(const bf16x8*)(sW + swzb(nf * 16 + lrow, kb2));
      acc2[0][nf] = __builtin_amdgcn_mfma_f32_16x16x32_bf16(a0, bfr, acc2[0][nf], 0, 0, 0);
      acc2[1][nf] = __builtin_amdgcn_mfma_f32_16x16x32_bf16(a1, bfr, acc2[1][nf], 0, 0, 0);
    }
  }
  __syncthreads(); // done reading sA/sW; reuse for stats reduce

  float* sred = (float*)sA;          // [4][128]
  float* qred = (float*)(sA + 2048); // [4][128]
  u16* zp = (u16*)z;
  #pragma unroll
  for (int nf = 0; nf < 8; ++nf) {
    const int col = nf * 16 + lrow;
    const float bb = b2[col];
    float s = 0.f, q = 0.f;
    #pragma unroll
    for (int mf = 0; mf < 2; ++mf) {
      #pragma unroll
      for (int j = 0; j < 4; ++j) {
        int grow = m0 + wm + mf * 16 + crow + j;
        if (grow < Nn) {
          float v = acc2[mf][nf][j] + bb;
          zp[(size_t)grow * Hd + col] = f2bf(v);
          s += v; q += v * v;
        }
      }
    }
    s += __shfl_xor(s, 16, 64); s += __shfl_xor(s, 32, 64);
    q += __shfl_xor(q, 16, 64); q += __shfl_xor(q, 32, 64);
    if (lane < 16) { sred[wave * 128 + col] = s; qred[wave * 128 + col] = q; }
  }
  __syncthreads();
  if (tid < 128) {
    float a = sred[tid] + sred[128 + tid] + sred[256 + tid] + sred[384 + tid];
    pstats[(size_t)blockIdx.x * 256 + tid] = a;
  } else {
    int c = tid - 128;
    float a = qred[c] + qred[128 + c] + qred[256 + c] + qred[384 + c];
    pstats[(size_t)blockIdx.x * 256 + tid] = a;
  }
}

// ---- reduce per-block stats partials ----
__global__ __launch_bounds__(256) void redstats_kernel(const float* __restrict__ pstats,
                                                       float* __restrict__ stats) {
  __shared__ float red[256];
  int slot = blockIdx.x, t = threadIdx.x;
  float a = 0.f;
  for (int i = t; i < NBLK; i += 256) a += pstats[(size_t)i * 256 + slot];
  red[t] = a;
  __syncthreads();
  for (int o = 128; o > 0; o >>= 1) {
    if (t < o) red[t] += red[t + o];
    __syncthreads();
  }
  if (t == 0) stats[slot] = red[0];
}

__global__ __launch_bounds__(128) void bnparam_kernel(const float* __restrict__ stats,
                                                      const float* __restrict__ gammas,
                                                      const float* __restrict__ betas,
                                                      int layer, float* __restrict__ ss) {
  int f = threadIdx.x;
  const float invn = 1.0f / (float)Nn;
  float mu = stats[f] * invn;
  float var = stats[Hd + f] * invn - mu * mu;
  float sc = gammas[layer * Hd + f] * rsqrtf(var + 1e-5f);
  ss[f] = sc;
  ss[Hd + f] = betas[layer * Hd + f] - mu * sc;
}

// ---- pooling of xb (bf16) ----
__global__ __launch_bounds__(128) void pool_kernel(const __hip_bfloat16* __restrict__ v,
                                                   const int* __restrict__ batch,
                                                   float* __restrict__ emb, int colOff) {
  int g = blockIdx.x / SPLIT, sp = blockIdx.x % SPLIT;
  int f = threadIdx.x;
  int lo = lower_bound_dev(batch, Nn, g);
  int hi = lower_bound_dev(batch, Nn, g + 1);
  int len = hi - lo;
  if (len <= 0) return;
  int chunk = (len + SPLIT - 1) / SPLIT;
  int rs = lo + sp * chunk;
  int re = min(rs + chunk, hi);
  if (rs >= re) return;
  const u16* vp = (const u16*)v;
  float acc = 0.f;
  for (int i = rs; i < re; ++i) acc += bf2f((u32)vp[(size_t)i * Hd + f]);
  atomicAdd(&emb[g * Din + colOff + f], acc);
}

// ---- fused BN apply + ReLU + write h (bf16) + pool ----
__global__ __launch_bounds__(128) void bn_pool_kernel(const __hip_bfloat16* __restrict__ z,
                                                      const float* __restrict__ ss,
                                                      const int* __restrict__ batch,
                                                      __hip_bfloat16* __restrict__ h,
                                                      float* __restrict__ emb, int colOff) {
  int g = blockIdx.x / SPLIT, sp = blockIdx.x % SPLIT;
  int c2 = (threadIdx.x & 63) * 2; // feature pair
  int rh = threadIdx.x >> 6;
  float sc0 = ss[c2], sh0 = ss[Hd + c2];
  float sc1 = ss[c2 + 1], sh1 = ss[Hd + c2 + 1];
  int lo = lower_bound_dev(batch, Nn, g);
  int hi = lower_bound_dev(batch, Nn, g + 1);
  int len = hi - lo;
  if (len <= 0) return;
  int chunk = (len + SPLIT - 1) / SPLIT;
  int rs = lo + sp * chunk;
  int re = min(rs + chunk, hi);
  if (rs >= re) return;
  const u16* zp = (const u16*)z;
  u16* hp = (u16*)h;
  float a0 = 0.f, a1 = 0.f;
  for (int i = rs + rh; i < re; i += 2) {
    u32 v = *(const u32*)(zp + (size_t)i * Hd + c2);
    float v0 = bf2f(v & 0xffffu) * sc0 + sh0; v0 = fmaxf(v0, 0.f);
    float v1 = bf2f(v >> 16) * sc1 + sh1; v1 = fmaxf(v1, 0.f);
    *(u32*)(hp + (size_t)i * Hd + c2) = (u32)f2bf(v0) | ((u32)f2bf(v1) << 16);
    a0 += v0; a1 += v1;
  }
  atomicAdd(&emb[g * Din + colOff + c2], a0);
  atomicAdd(&emb[g * Din + colOff + c2 + 1], a1);
}

// ---- output head: out = emb @ Wout + bout ----
__global__ __launch_bounds__(64) void out_kernel(const float* __restrict__ emb, const float* __restrict__ Wout,
                                                 const float* __restrict__ bout, float* __restrict__ out) {
  int g = blockIdx.x;
  int lane = threadIdx.x;
  float acc[Oo];
  #pragma unroll
  for (int o = 0; o < Oo; ++o) acc[o] = 0.f;
  for (int d = lane; d < Din; d += 64) {
    float ev = emb[g * Din + d];
    #pragma unroll
    for (int o = 0; o < Oo; ++o) acc[o] += ev * Wout[d * Oo + o];
  }
  #pragma unroll
  for (int off = 32; off > 0; off >>= 1) {
    #pragma unroll
    for (int o = 0; o < Oo; ++o) acc[o] += __shfl_down(acc[o], off, 64);
  }
  if (lane == 0) {
    #pragma unroll
    for (int o = 0; o < Oo; ++o) out[g * Oo + o] = acc[o] + bout[o];
  }
}

extern "C" void kernel_launch(void* const* d_in, const int* in_sizes, int n_in,
                              void* d_out, int out_size, void* d_ws, size_t ws_size,
                              hipStream_t stream) {
  (void)in_sizes; (void)n_in; (void)out_size;
  const float* x = (const float*)d_in[0];
  const int* ei = (const int*)d_in[1];
  const int* src = ei;
  const int* dst = ei + Ee;
  const int* batch = (const int*)d_in[2];
  const float* W1s = (const float*)d_in[3];
  const float* b1s = (const float*)d_in[4];
  const float* W2s = (const float*)d_in[5];
  const float* b2s = (const float*)d_in[6];
  const float* eps = (const float*)d_in[7];
  const float* gammas = (const float*)d_in[8];
  const float* betas = (const float*)d_in[9];
  const float* Wout = (const float*)d_in[10];
  const float* bout = (const float*)d_in[11];
  float* out = (float*)d_out;

  unsigned char* ws = (unsigned char*)d_ws;
  size_t off = 0;
  auto alloc = [&](size_t bytes) -> void* {
    void* p = ws + off;
    off = (off + bytes + 255) & ~size_t(255);
    return p;
  };
  __hip_bfloat16* xb = (__hip_bfloat16*)alloc((size_t)Nn * Hd * 2);
  __hip_bfloat16* h = (__hip_bfloat16*)alloc((size_t)Nn * Hd * 2);
  __hip_bfloat16* z = (__hip_bfloat16*)alloc((size_t)Nn * Hd * 2);
  __hip_bfloat16* t = (__hip_bfloat16*)alloc((size_t)Nn * Hd * 2);
  int* indptr = (int*)alloc((size_t)(Nn + 1) * 4);
  int* adj = (int*)alloc((size_t)Ee * 4);
  u32* buckets = (u32*)alloc((size_t)NB * BCAP * 4);
  int* gptr = (int*)alloc((size_t)NB * 4);
  int* bmeta = (int*)alloc((size_t)2 * NB * 4);
  float* emb = (float*)alloc((size_t)Gg * Din * 4);
  float* pstats = (float*)alloc((size_t)NBLK * 256 * 4);
  float* stats = (float*)alloc(256 * 4);
  float* ss = (float*)alloc(256 * 4);
  __hip_bfloat16* wt = (__hip_bfloat16*)alloc((size_t)Ll * 2 * Hd * Hd * 2);
  if (off > ws_size) return; // workspace too small -> leave output poisoned (visible failure)

  hipMemsetAsync(emb, 0, (size_t)Gg * Din * 4, stream);

  xcvt_kernel<<<(Nn * Hd / 8 + 255) / 256, 256, 0, stream>>>(x, xb);
  wprep_kernel<<<(Ll * 2 * Hd * Hd + 255) / 256, 256, 0, stream>>>(W1s, W2s, wt);

  // bucketed CSR build
  initgptr_kernel<<<1, NB, 0, stream>>>(gptr);
  binA_kernel<<<NBATCH, 256, 0, stream>>>(src, dst, gptr, buckets);
  bucketscan_kernel<<<1, NB, 0, stream>>>(gptr, bmeta, indptr);
  place_kernel<<<NB, 512, 0, stream>>>(buckets, bmeta, indptr, adj);

  pool_kernel<<<Gg * SPLIT, 128, 0, stream>>>(xb, batch, emb, 0);

  const __hip_bfloat16* hcur = xb;
  for (int l = 0; l < Ll; ++l) {
    agg_kernel<<<(Nn + 3) / 4, 256, 0, stream>>>(hcur, indptr, adj, eps, l, t);
    mlp_kernel<<<NBLK, 256, 0, stream>>>(
        t, wt + (size_t)l * 2 * Hd * Hd, wt + (size_t)l * 2 * Hd * Hd + Hd * Hd,
        b1s + l * Hd, b2s + l * Hd, z, pstats);
    redstats_kernel<<<256, 256, 0, stream>>>(pstats, stats);
    bnparam_kernel<<<1, 128, 0, stream>>>(stats, gammas, betas, l, ss);
    bn_pool_kernel<<<Gg * SPLIT, 128, 0, stream>>>(z, ss, batch, h, emb, Hd + l * Hd);
    hcur = h;
  }

  out_kernel<<<Gg, 64, 0, stream>>>(emb, Wout, bout, out);
}

// Round 4
// 592.442 us; speedup vs baseline: 3.4951x; 1.0157x over previous
//
#include <hip/hip_runtime.h>
#include <hip/hip_bf16.h>

typedef __attribute__((ext_vector_type(8))) __bf16 bf16x8;
typedef __attribute__((ext_vector_type(4))) float f32x4;
typedef unsigned short u16;
typedef unsigned int u32;

constexpr int Nn = 100000;
constexpr int Ee = 1600000;
constexpr int Hd = 128;          // F == H == 128
constexpr int Ll = 4;
constexpr int Gg = 512;
constexpr int Oo = 10;
constexpr int Din = Hd + Ll * Hd; // 640
constexpr int SPLIT = 8;
constexpr int NBLK = (Nn + 127) / 128; // 782 MLP tiles

// ---- bucketed CSR build params ----
constexpr int NB = 256;               // buckets
constexpr int NPB = 392;              // nodes per bucket (256*392 = 100352 >= Nn)
constexpr int BCAP = 8192;            // bucket capacity (avg 6250, +24 sigma safe)
constexpr int BATCH = 8192;           // edges per binA block
constexpr int NBATCH = (Ee + BATCH - 1) / BATCH; // 196

__device__ __forceinline__ int swzb(int row, int bc) {
  // byte offset into a 128x128 bf16 tile (256 B/row), XOR-swizzled (T2, st-style)
  return (row << 8) + (bc ^ ((row & 7) << 4));
}

__device__ __forceinline__ u16 f2bf(float f) {
  __hip_bfloat16 b = __float2bfloat16(f);
  u16 u;
  __builtin_memcpy(&u, &b, 2);
  return u;
}

__device__ __forceinline__ float bf2f(u32 u) { return __uint_as_float(u << 16); }

__device__ __forceinline__ int lower_bound_dev(const int* a, int n, int key) {
  int lo = 0, hi = n;
  while (lo < hi) { int mid = (lo + hi) >> 1; if (a[mid] < key) lo = mid + 1; else hi = mid; }
  return lo;
}

// ---- x f32 -> bf16 ----
__global__ __launch_bounds__(256) void xcvt_kernel(const float* __restrict__ x, __hip_bfloat16* __restrict__ xb) {
  int i = blockIdx.x * 256 + threadIdx.x; // unit of 8 elements
  const int total = Nn * Hd / 8;
  if (i >= total) return;
  f32x4 v0 = *(const f32x4*)(x + (size_t)i * 8);
  f32x4 v1 = *(const f32x4*)(x + (size_t)i * 8 + 4);
  uint4 o;
  o.x = (u32)f2bf(v0[0]) | ((u32)f2bf(v0[1]) << 16);
  o.y = (u32)f2bf(v0[2]) | ((u32)f2bf(v0[3]) << 16);
  o.z = (u32)f2bf(v1[0]) | ((u32)f2bf(v1[1]) << 16);
  o.w = (u32)f2bf(v1[2]) | ((u32)f2bf(v1[3]) << 16);
  *(uint4*)((u16*)xb + (size_t)i * 8) = o;
}

// ---- weight prep: W1s/W2s f32 [l][k][n] -> wt bf16 [l][w][n][k] (transposed) ----
__global__ __launch_bounds__(256) void wprep_kernel(const float* __restrict__ W1s,
                                                    const float* __restrict__ W2s,
                                                    __hip_bfloat16* __restrict__ wt) {
  int idx = blockIdx.x * 256 + threadIdx.x;
  if (idx >= Ll * 2 * Hd * Hd) return;
  int l = idx >> 15;
  int w = (idx >> 14) & 1;
  int nn = (idx >> 7) & 127;
  int k = idx & 127;
  const float* W = w ? W2s : W1s;
  wt[idx] = __float2bfloat16(W[l * Hd * Hd + k * Hd + nn]);
}

// ---- bucketed CSR build ----
__global__ void initgptr_kernel(int* __restrict__ gptr) {
  int i = threadIdx.x;
  if (i < NB) gptr[i] = i * BCAP;
}

// Phase A: bin edges by dst-bucket with LDS reorder so global writes are coalesced
__global__ __launch_bounds__(256) void binA_kernel(const int* __restrict__ src, const int* __restrict__ dst,
                                                   int* __restrict__ gptr, u32* __restrict__ buckets) {
  __shared__ int hist[NB];
  __shared__ int lbase[NB];
  __shared__ int lpos[NB];
  __shared__ int gbaseS[NB];
  __shared__ int scanT[NB];
  __shared__ u32 reorder[BATCH];
  const int tid = threadIdx.x;
  const int e0 = blockIdx.x * BATCH;
  const int n = min(BATCH, Ee - e0);

  hist[tid] = 0;
  __syncthreads();
  for (int k = tid; k < n; k += 256) {
    int d = dst[e0 + k];
    atomicAdd(&hist[d / NPB], 1);
  }
  __syncthreads();
  // exclusive scan hist -> lbase
  int v = hist[tid];
  scanT[tid] = v;
  __syncthreads();
  for (int off = 1; off < NB; off <<= 1) {
    int x = (tid >= off) ? scanT[tid - off] : 0;
    __syncthreads();
    scanT[tid] += x;
    __syncthreads();
  }
  lbase[tid] = scanT[tid] - v;
  lpos[tid] = 0;
  __syncthreads();
  // reorder into bucket-grouped LDS
  for (int k = tid; k < n; k += 256) {
    int d = dst[e0 + k];
    int s = src[e0 + k];
    int b = d / NPB;
    int dlo = d - b * NPB;
    int p = lbase[b] + atomicAdd(&lpos[b], 1);
    reorder[p] = ((u32)dlo << 17) | (u32)s;
  }
  __syncthreads();
  // claim global ranges
  if (hist[tid] > 0) gbaseS[tid] = atomicAdd(&gptr[tid], hist[tid]);
  __syncthreads();
  // flat coalesced flush (binary search bucket per position)
  for (int p = tid; p < n; p += 256) {
    int lo = 0, hi = NB - 1;
    while (lo < hi) { int mid = (lo + hi + 1) >> 1; if (lbase[mid] <= p) lo = mid; else hi = mid - 1; }
    buckets[gbaseS[lo] + (p - lbase[lo])] = reorder[p];
  }
}

// tiny scan over bucket counts -> adj bases; also terminator of indptr
__global__ __launch_bounds__(256) void bucketscan_kernel(const int* __restrict__ gptr,
                                                         int* __restrict__ bmeta,
                                                         int* __restrict__ indptr) {
  __shared__ int sc[NB];
  int tid = threadIdx.x;
  int cnt = gptr[tid] - tid * BCAP;
  sc[tid] = cnt;
  __syncthreads();
  for (int off = 1; off < NB; off <<= 1) {
    int x = (tid >= off) ? sc[tid - off] : 0;
    __syncthreads();
    sc[tid] += x;
    __syncthreads();
  }
  bmeta[tid] = cnt;
  bmeta[NB + tid] = sc[tid] - cnt; // exclusive = adj base
  if (tid == 0) indptr[Nn] = Ee;
}

// Phase B: per-bucket node histogram + placement (block-local scatter window)
__global__ __launch_bounds__(512) void place_kernel(const u32* __restrict__ buckets,
                                                    const int* __restrict__ bmeta,
                                                    int* __restrict__ indptr, int* __restrict__ adj) {
  __shared__ int ncnt[512];
  __shared__ int nofs[NPB];
  __shared__ int lcur[NPB];
  const int tid = threadIdx.x;
  const int b = blockIdx.x;
  const int cnt = bmeta[b];
  const int adjbase = bmeta[NB + b];
  const int ebase = b * BCAP;
  const int node0 = b * NPB;
  const int nnodes = min(NPB, Nn - node0);

  ncnt[tid] = 0;
  if (tid < NPB) lcur[tid] = 0;
  __syncthreads();
  for (int k = tid; k < cnt; k += 512) atomicAdd(&ncnt[buckets[ebase + k] >> 17], 1);
  __syncthreads();
  int v = ncnt[tid];
  for (int off = 1; off < 512; off <<= 1) {
    int x = (tid >= off) ? ncnt[tid - off] : 0;
    __syncthreads();
    ncnt[tid] += x;
    __syncthreads();
  }
  if (tid < NPB) nofs[tid] = ncnt[tid] - v;
  __syncthreads();
  if (tid < nnodes) indptr[node0 + tid] = adjbase + nofs[tid];
  for (int k = tid; k < cnt; k += 512) {
    u32 u = buckets[ebase + k];
    int dlo = u >> 17;
    int s = (int)(u & 0x1FFFFu);
    int p = atomicAdd(&lcur[dlo], 1);
    adj[adjbase + nofs[dlo] + p] = s;
  }
}

// ---- aggregation: t = bf16((1+eps)*h + sum_{nbr} h[nbr]); one wave per node ----
// Tiered 16/8/4/1 neighbor-load batches: uniform adj indices -> SGPR base loads,
// up to 16 outstanding 256B row-gathers per wave to cover L2/L3 latency.
__global__ __launch_bounds__(256) void agg_kernel(const __hip_bfloat16* __restrict__ hb,
                                                  const int* __restrict__ indptr,
                                                  const int* __restrict__ adj,
                                                  const float* __restrict__ epsp,
                                                  int layer, __hip_bfloat16* __restrict__ t) {
  int wid = blockIdx.x * 4 + (threadIdx.x >> 6); // node
  if (wid >= Nn) return;
  int lane = threadIdx.x & 63;
  int cb = lane * 2; // feature pair base
  const u16* hp = (const u16*)hb;
  u32 selfu = *(const u32*)(hp + (size_t)wid * Hd + cb);
  float eps1 = 1.0f + epsp[layer];
  int s = __builtin_amdgcn_readfirstlane(indptr[wid]);
  int e = __builtin_amdgcn_readfirstlane(indptr[wid + 1]);
  float a0 = 0.f, a1 = 0.f;
  int p = s;
  while (p + 16 <= e) {
    u32 v[16];
    #pragma unroll
    for (int j = 0; j < 16; ++j) v[j] = *(const u32*)(hp + (size_t)adj[p + j] * Hd + cb);
    #pragma unroll
    for (int j = 0; j < 16; ++j) { a0 += bf2f(v[j] & 0xffffu); a1 += bf2f(v[j] >> 16); }
    p += 16;
  }
  if (p + 8 <= e) {
    u32 v[8];
    #pragma unroll
    for (int j = 0; j < 8; ++j) v[j] = *(const u32*)(hp + (size_t)adj[p + j] * Hd + cb);
    #pragma unroll
    for (int j = 0; j < 8; ++j) { a0 += bf2f(v[j] & 0xffffu); a1 += bf2f(v[j] >> 16); }
    p += 8;
  }
  if (p + 4 <= e) {
    u32 v[4];
    #pragma unroll
    for (int j = 0; j < 4; ++j) v[j] = *(const u32*)(hp + (size_t)adj[p + j] * Hd + cb);
    #pragma unroll
    for (int j = 0; j < 4; ++j) { a0 += bf2f(v[j] & 0xffffu); a1 += bf2f(v[j] >> 16); }
    p += 4;
  }
  for (; p < e; ++p) {
    u32 v0 = *(const u32*)(hp + (size_t)adj[p] * Hd + cb);
    a0 += bf2f(v0 & 0xffffu);
    a1 += bf2f(v0 >> 16);
  }
  a0 += eps1 * bf2f(selfu & 0xffffu);
  a1 += eps1 * bf2f(selfu >> 16);
  u32 outv = (u32)f2bf(a0) | ((u32)f2bf(a1) << 16);
  *(u32*)((u16*)t + (size_t)wid * Hd + cb) = outv;
}

// ---- fused 2-GEMM MLP + BN partial stats: z = relu(t@W1+b1)@W2 + b2 ----
__global__ __launch_bounds__(256) void mlp_kernel(const __hip_bfloat16* __restrict__ t,
                                                  const __hip_bfloat16* __restrict__ w1t,
                                                  const __hip_bfloat16* __restrict__ w2t,
                                                  const float* __restrict__ b1,
                                                  const float* __restrict__ b2,
                                                  __hip_bfloat16* __restrict__ z,
                                                  float* __restrict__ pstats) {
  __shared__ __align__(16) unsigned char sA[32 * 1024]; // A tile, then U tile
  __shared__ __align__(16) unsigned char sW[32 * 1024]; // W1t, then W2t
  const int tid = threadIdx.x;
  const int m0 = blockIdx.x * 128;

  // stage A rows + W1t (swizzled)
  for (int c = tid; c < 2048; c += 256) {
    int row = c >> 4, bc = (c & 15) << 4;
    int so = swzb(row, bc);
    *(uint4*)(sW + so) = *(const uint4*)((const unsigned char*)w1t + row * 256 + bc);
    uint4 av = make_uint4(0u, 0u, 0u, 0u);
    int gr = m0 + row;
    if (gr < Nn) av = *(const uint4*)((const unsigned char*)t + (size_t)gr * 256 + bc);
    *(uint4*)(sA + so) = av;
  }
  __syncthreads();

  const int lane = tid & 63;
  const int wave = tid >> 6;
  const int lrow = lane & 15;
  const int lkb = (lane >> 4) << 4;   // byte offset of this lane's k-octet
  const int wm = wave * 32;           // wave's 32 output rows
  const int crow = (lane >> 4) << 2;  // C/D row base

  f32x4 acc[2][8];
  #pragma unroll
  for (int a = 0; a < 2; ++a) {
    #pragma unroll
    for (int b = 0; b < 8; ++b) acc[a][b] = (f32x4){0.f, 0.f, 0.f, 0.f};
  }

  #pragma unroll
  for (int kk = 0; kk < 4; ++kk) {
    const int kb2 = kk * 64 + lkb;
    bf16x8 a0 = *(const bf16x8*)(sA + swzb(wm + lrow, kb2));
    bf16x8 a1 = *(const bf16x8*)(sA + swzb(wm + 16 + lrow, kb2));
    #pragma unroll
    for (int nf = 0; nf < 8; ++nf) {
      bf16x8 bfr = *(const bf16x8*)(sW + swzb(nf * 16 + lrow, kb2));
      acc[0][nf] = __builtin_amdgcn_mfma_f32_16x16x32_bf16(a0, bfr, acc[0][nf], 0, 0, 0);
      acc[1][nf] = __builtin_amdgcn_mfma_f32_16x16x32_bf16(a1, bfr, acc[1][nf], 0, 0, 0);
    }
  }
  __syncthreads();

  // stage W2t; write U = bf16(relu(acc + b1)) into sA (same swizzle)
  for (int c = tid; c < 2048; c += 256) {
    int row = c >> 4, bc = (c & 15) << 4;
    *(uint4*)(sW + swzb(row, bc)) = *(const uint4*)((const unsigned char*)w2t + row * 256 + bc);
  }
  #pragma unroll
  for (int nf = 0; nf < 8; ++nf) {
    const int col = nf * 16 + lrow;
    const float bb = b1[col];
    #pragma unroll
    for (int mf = 0; mf < 2; ++mf) {
      #pragma unroll
      for (int j = 0; j < 4; ++j) {
        float v = acc[mf][nf][j] + bb;
        v = v > 0.f ? v : 0.f;
        int row = wm + mf * 16 + crow + j;
        *(u16*)(sA + swzb(row, col * 2)) = f2bf(v);
      }
    }
  }
  __syncthreads();

  f32x4 acc2[2][8];
  #pragma unroll
  for (int a = 0; a < 2; ++a) {
    #pragma unroll
    for (int b = 0; b < 8; ++b) acc2[a][b] = (f32x4){0.f, 0.f, 0.f, 0.f};
  }
  #pragma unroll
  for (int kk = 0; kk < 4; ++kk) {
    const int kb2 = kk * 64 + lkb;
    bf16x8 a0 = *(const bf16x8*)(sA + swzb(wm + lrow, kb2));
    bf16x8 a1 = *(const bf16x8*)(sA + swzb(wm + 16 + lrow, kb2));
    #pragma unroll
    for (int nf = 0; nf < 8; ++nf) {
      bf16x8 bfr = *(const bf16x8*)(sW + swzb(nf * 16 + lrow, kb2));
      acc2[0][nf] = __builtin_amdgcn_mfma_f32_16x16x32_bf16(a0, bfr, acc2[0][nf], 0, 0, 0);
      acc2[1][nf] = __builtin_amdgcn_mfma_f32_16x16x32_bf16(a1, bfr, acc2[1][nf], 0, 0, 0);
    }
  }
  __syncthreads(); // done reading sA/sW; reuse for stats reduce

  float* sred = (float*)sA;          // [4][128]
  float* qred = (float*)(sA + 2048); // [4][128]
  u16* zp = (u16*)z;
  #pragma unroll
  for (int nf = 0; nf < 8; ++nf) {
    const int col = nf * 16 + lrow;
    const float bb = b2[col];
    float s = 0.f, q = 0.f;
    #pragma unroll
    for (int mf = 0; mf < 2; ++mf) {
      #pragma unroll
      for (int j = 0; j < 4; ++j) {
        int grow = m0 + wm + mf * 16 + crow + j;
        if (grow < Nn) {
          float v = acc2[mf][nf][j] + bb;
          zp[(size_t)grow * Hd + col] = f2bf(v);
          s += v; q += v * v;
        }
      }
    }
    s += __shfl_xor(s, 16, 64); s += __shfl_xor(s, 32, 64);
    q += __shfl_xor(q, 16, 64); q += __shfl_xor(q, 32, 64);
    if (lane < 16) { sred[wave * 128 + col] = s; qred[wave * 128 + col] = q; }
  }
  __syncthreads();
  if (tid < 128) {
    float a = sred[tid] + sred[128 + tid] + sred[256 + tid] + sred[384 + tid];
    pstats[(size_t)blockIdx.x * 256 + tid] = a;
  } else {
    int c = tid - 128;
    float a = qred[c] + qred[128 + c] + qred[256 + c] + qred[384 + c];
    pstats[(size_t)blockIdx.x * 256 + tid] = a;
  }
}

// ---- fused stats reduce + BN param: one block per feature ----
__global__ __launch_bounds__(256) void stats_bn_kernel(const float* __restrict__ pstats,
                                                       const float* __restrict__ gammas,
                                                       const float* __restrict__ betas,
                                                       int layer, float* __restrict__ ss) {
  __shared__ float reds[256];
  __shared__ float redq[256];
  int f = blockIdx.x; // 0..127
  int t = threadIdx.x;
  float s = 0.f, q = 0.f;
  for (int i = t; i < NBLK; i += 256) {
    s += pstats[(size_t)i * 256 + f];
    q += pstats[(size_t)i * 256 + 128 + f];
  }
  reds[t] = s; redq[t] = q;
  __syncthreads();
  for (int o = 128; o > 0; o >>= 1) {
    if (t < o) { reds[t] += reds[t + o]; redq[t] += redq[t + o]; }
    __syncthreads();
  }
  if (t == 0) {
    const float invn = 1.0f / (float)Nn;
    float mu = reds[0] * invn;
    float var = redq[0] * invn - mu * mu;
    float sc = gammas[layer * Hd + f] * rsqrtf(var + 1e-5f);
    ss[f] = sc;
    ss[Hd + f] = betas[layer * Hd + f] - mu * sc;
  }
}

// ---- pooling of xb (bf16, vectorized u32 pair loads) ----
__global__ __launch_bounds__(128) void pool_kernel(const __hip_bfloat16* __restrict__ v,
                                                   const int* __restrict__ batch,
                                                   float* __restrict__ emb, int colOff) {
  int g = blockIdx.x / SPLIT, sp = blockIdx.x % SPLIT;
  int c2 = (threadIdx.x & 63) * 2; // feature pair
  int rh = threadIdx.x >> 6;
  int lo = lower_bound_dev(batch, Nn, g);
  int hi = lower_bound_dev(batch, Nn, g + 1);
  int len = hi - lo;
  if (len <= 0) return;
  int chunk = (len + SPLIT - 1) / SPLIT;
  int rs = lo + sp * chunk;
  int re = min(rs + chunk, hi);
  if (rs >= re) return;
  const u16* vp = (const u16*)v;
  float a0 = 0.f, a1 = 0.f;
  for (int i = rs + rh; i < re; i += 2) {
    u32 u = *(const u32*)(vp + (size_t)i * Hd + c2);
    a0 += bf2f(u & 0xffffu);
    a1 += bf2f(u >> 16);
  }
  atomicAdd(&emb[g * Din + colOff + c2], a0);
  atomicAdd(&emb[g * Din + colOff + c2 + 1], a1);
}

// ---- fused BN apply + ReLU + write h (bf16) + pool ----
__global__ __launch_bounds__(128) void bn_pool_kernel(const __hip_bfloat16* __restrict__ z,
                                                      const float* __restrict__ ss,
                                                      const int* __restrict__ batch,
                                                      __hip_bfloat16* __restrict__ h,
                                                      float* __restrict__ emb, int colOff) {
  int g = blockIdx.x / SPLIT, sp = blockIdx.x % SPLIT;
  int c2 = (threadIdx.x & 63) * 2; // feature pair
  int rh = threadIdx.x >> 6;
  float sc0 = ss[c2], sh0 = ss[Hd + c2];
  float sc1 = ss[c2 + 1], sh1 = ss[Hd + c2 + 1];
  int lo = lower_bound_dev(batch, Nn, g);
  int hi = lower_bound_dev(batch, Nn, g + 1);
  int len = hi - lo;
  if (len <= 0) return;
  int chunk = (len + SPLIT - 1) / SPLIT;
  int rs = lo + sp * chunk;
  int re = min(rs + chunk, hi);
  if (rs >= re) return;
  const u16* zp = (const u16*)z;
  u16* hp = (u16*)h;
  float a0 = 0.f, a1 = 0.f;
  for (int i = rs + rh; i < re; i += 2) {
    u32 v = *(const u32*)(zp + (size_t)i * Hd + c2);
    float v0 = bf2f(v & 0xffffu) * sc0 + sh0; v0 = fmaxf(v0, 0.f);
    float v1 = bf2f(v >> 16) * sc1 + sh1; v1 = fmaxf(v1, 0.f);
    *(u32*)(hp + (size_t)i * Hd + c2) = (u32)f2bf(v0) | ((u32)f2bf(v1) << 16);
    a0 += v0; a1 += v1;
  }
  atomicAdd(&emb[g * Din + colOff + c2], a0);
  atomicAdd(&emb[g * Din + colOff + c2 + 1], a1);
}

// ---- output head: out = emb @ Wout + bout ----
__global__ __launch_bounds__(64) void out_kernel(const float* __restrict__ emb, const float* __restrict__ Wout,
                                                 const float* __restrict__ bout, float* __restrict__ out) {
  int g = blockIdx.x;
  int lane = threadIdx.x;
  float acc[Oo];
  #pragma unroll
  for (int o = 0; o < Oo; ++o) acc[o] = 0.f;
  for (int d = lane; d < Din; d += 64) {
    float ev = emb[g * Din + d];
    #pragma unroll
    for (int o = 0; o < Oo; ++o) acc[o] += ev * Wout[d * Oo + o];
  }
  #pragma unroll
  for (int off = 32; off > 0; off >>= 1) {
    #pragma unroll
    for (int o = 0; o < Oo; ++o) acc[o] += __shfl_down(acc[o], off, 64);
  }
  if (lane == 0) {
    #pragma unroll
    for (int o = 0; o < Oo; ++o) out[g * Oo + o] = acc[o] + bout[o];
  }
}

extern "C" void kernel_launch(void* const* d_in, const int* in_sizes, int n_in,
                              void* d_out, int out_size, void* d_ws, size_t ws_size,
                              hipStream_t stream) {
  (void)in_sizes; (void)n_in; (void)out_size;
  const float* x = (const float*)d_in[0];
  const int* ei = (const int*)d_in[1];
  const int* src = ei;
  const int* dst = ei + Ee;
  const int* batch = (const int*)d_in[2];
  const float* W1s = (const float*)d_in[3];
  const float* b1s = (const float*)d_in[4];
  const float* W2s = (const float*)d_in[5];
  const float* b2s = (const float*)d_in[6];
  const float* eps = (const float*)d_in[7];
  const float* gammas = (const float*)d_in[8];
  const float* betas = (const float*)d_in[9];
  const float* Wout = (const float*)d_in[10];
  const float* bout = (const float*)d_in[11];
  float* out = (float*)d_out;

  unsigned char* ws = (unsigned char*)d_ws;
  size_t off = 0;
  auto alloc = [&](size_t bytes) -> void* {
    void* p = ws + off;
    off = (off + bytes + 255) & ~size_t(255);
    return p;
  };
  __hip_bfloat16* xb = (__hip_bfloat16*)alloc((size_t)Nn * Hd * 2);
  __hip_bfloat16* h = (__hip_bfloat16*)alloc((size_t)Nn * Hd * 2);
  __hip_bfloat16* z = (__hip_bfloat16*)alloc((size_t)Nn * Hd * 2);
  __hip_bfloat16* t = (__hip_bfloat16*)alloc((size_t)Nn * Hd * 2);
  int* indptr = (int*)alloc((size_t)(Nn + 1) * 4);
  int* adj = (int*)alloc((size_t)Ee * 4);
  u32* buckets = (u32*)alloc((size_t)NB * BCAP * 4);
  int* gptr = (int*)alloc((size_t)NB * 4);
  int* bmeta = (int*)alloc((size_t)2 * NB * 4);
  float* emb = (float*)alloc((size_t)Gg * Din * 4);
  float* pstats = (float*)alloc((size_t)NBLK * 256 * 4);
  float* ss = (float*)alloc(256 * 4);
  __hip_bfloat16* wt = (__hip_bfloat16*)alloc((size_t)Ll * 2 * Hd * Hd * 2);
  if (off > ws_size) return; // workspace too small -> leave output poisoned (visible failure)

  hipMemsetAsync(emb, 0, (size_t)Gg * Din * 4, stream);

  xcvt_kernel<<<(Nn * Hd / 8 + 255) / 256, 256, 0, stream>>>(x, xb);
  wprep_kernel<<<(Ll * 2 * Hd * Hd + 255) / 256, 256, 0, stream>>>(W1s, W2s, wt);

  // bucketed CSR build
  initgptr_kernel<<<1, NB, 0, stream>>>(gptr);
  binA_kernel<<<NBATCH, 256, 0, stream>>>(src, dst, gptr, buckets);
  bucketscan_kernel<<<1, NB, 0, stream>>>(gptr, bmeta, indptr);
  place_kernel<<<NB, 512, 0, stream>>>(buckets, bmeta, indptr, adj);

  pool_kernel<<<Gg * SPLIT, 128, 0, stream>>>(xb, batch, emb, 0);

  const __hip_bfloat16* hcur = xb;
  for (int l = 0; l < Ll; ++l) {
    agg_kernel<<<(Nn + 3) / 4, 256, 0, stream>>>(hcur, indptr, adj, eps, l, t);
    mlp_kernel<<<NBLK, 256, 0, stream>>>(
        t, wt + (size_t)l * 2 * Hd * Hd, wt + (size_t)l * 2 * Hd * Hd + Hd * Hd,
        b1s + l * Hd, b2s + l * Hd, z, pstats);
    stats_bn_kernel<<<128, 256, 0, stream>>>(pstats, gammas, betas, l, ss);
    bn_pool_kernel<<<Gg * SPLIT, 128, 0, stream>>>(z, ss, batch, h, emb, Hd + l * Hd);
    hcur = h;
  }

  out_kernel<<<Gg, 64, 0, stream>>>(emb, Wout, bout, out);
}